// Round 5
// baseline (1446.561 us; speedup 1.0000x reference)
//
#include <hip/hip_runtime.h>
#include <hip/hip_bf16.h>
#include <math.h>

typedef short bf16x8 __attribute__((ext_vector_type(8)));
typedef float f32x4 __attribute__((ext_vector_type(4)));

#define B_   128
#define T_   800
#define E_   100
#define HC   192       // 2H
#define OUTV 102400    // B*C*O

__device__ inline float squash_scale(float n2) {
    return (n2 / (n2 + 1.f)) * rsqrtf(fmaxf(n2, 1e-30f));
}

__device__ inline unsigned short bf16_bits(float x) {
    __hip_bfloat16 h = __float2bfloat16(x);
    return *(unsigned short*)&h;
}

__device__ inline unsigned int pack_bf16x2(float a, float b) {
    return (unsigned int)bf16_bits(a) | ((unsigned int)bf16_bits(b) << 16);
}

// split x into hi (bf16) + lo (bf16 of residual); hi+lo ~ fp32-accurate weight
__device__ inline void split_hilo(float x, unsigned short& hi, unsigned short& lo) {
    __hip_bfloat16 h = __float2bfloat16(x);
    float hf = __bfloat162float(h);
    hi = *(unsigned short*)&h;
    __hip_bfloat16 l = __float2bfloat16(x - hf);
    lo = *(unsigned short*)&l;
}

// ---------------------------------------------------------------------------
// Kernel A: gi = gather(emb, tokens[chunk]) @ wih^T + bih  for ONE direction.
// emb staged as single bf16; wih staged as hi+lo bf16 planes.
// ---------------------------------------------------------------------------
__global__ __launch_bounds__(256) void k_gi(const int* __restrict__ tokens,
        const float* __restrict__ emb,
        const float* __restrict__ wih,
        const float* __restrict__ bih,
        __hip_bfloat16* __restrict__ gi,
        int t0, int TC)
{
    const int m0 = blockIdx.x * 64;
    const int n0 = blockIdx.y * 64;      // 0,64,128,192,256
    const int tid = threadIdx.x;
    __shared__ __align__(16) unsigned short At[64 * 136];   // 64 x 128, stride 136
    __shared__ __align__(16) unsigned short Bhi[64 * 136];
    __shared__ __align__(16) unsigned short Blo[64 * 136];
    __shared__ int tok[64];
    if (tid < 64) {
        int cr = m0 + tid;
        tok[tid] = tokens[(cr / TC) * T_ + t0 + (cr % TC)];
    }
    __syncthreads();
    for (int idx = tid; idx < 64 * 64; idx += 256) {
        int r = idx >> 6, p = idx & 63;          // p = column pair
        unsigned int v = 0;
        if (p < 50) {
            float2 f = *(const float2*)(emb + (size_t)tok[r] * E_ + 2 * p);
            v = pack_bf16x2(f.x, f.y);
        }
        *(unsigned int*)(&At[r * 136 + 2 * p]) = v;
    }
    for (int idx = tid; idx < 64 * 64; idx += 256) {
        int nn = idx >> 6, p = idx & 63;
        int gc = n0 + nn;
        unsigned int vh = 0, vl = 0;
        if (p < 50 && gc < 288) {
            float2 f = *(const float2*)(wih + (size_t)gc * E_ + 2 * p);
            unsigned short h0, l0, h1, l1;
            split_hilo(f.x, h0, l0);
            split_hilo(f.y, h1, l1);
            vh = (unsigned int)h0 | ((unsigned int)h1 << 16);
            vl = (unsigned int)l0 | ((unsigned int)l1 << 16);
        }
        *(unsigned int*)(&Bhi[nn * 136 + 2 * p]) = vh;
        *(unsigned int*)(&Blo[nn * 136 + 2 * p]) = vl;
    }
    __syncthreads();
    const int w = tid >> 6, l = tid & 63;
    const int lr = l & 15, quad = l >> 4;
    f32x4 z4 = {0.f, 0.f, 0.f, 0.f};
    f32x4 acc[4];
#pragma unroll
    for (int i = 0; i < 4; ++i) acc[i] = z4;
#pragma unroll
    for (int kk = 0; kk < 4; ++kk) {
        bf16x8 af = *(const bf16x8*)(&At[(w * 16 + lr) * 136 + kk * 32 + quad * 8]);
#pragma unroll
        for (int ns = 0; ns < 4; ++ns) {
            bf16x8 bh = *(const bf16x8*)(&Bhi[(ns * 16 + lr) * 136 + kk * 32 + quad * 8]);
            bf16x8 bl = *(const bf16x8*)(&Blo[(ns * 16 + lr) * 136 + kk * 32 + quad * 8]);
            acc[ns] = __builtin_amdgcn_mfma_f32_16x16x32_bf16(af, bh, acc[ns], 0, 0, 0);
            acc[ns] = __builtin_amdgcn_mfma_f32_16x16x32_bf16(af, bl, acc[ns], 0, 0, 0);
        }
    }
#pragma unroll
    for (int ns = 0; ns < 4; ++ns) {
        int gcol = n0 + ns * 16 + lr;
        if (gcol < 288) {
            float bias = bih[gcol];
#pragma unroll
            for (int r2 = 0; r2 < 4; ++r2) {
                int grow = m0 + w * 16 + quad * 4 + r2;
                gi[(size_t)grow * 288 + gcol] = __float2bfloat16(acc[ns][r2] + bias);
            }
        }
    }
}

// ---------------------------------------------------------------------------
// Kernel B: GRU recurrence for ONE direction, chains t0..t0+TC-1.
// ---------------------------------------------------------------------------
__global__ __launch_bounds__(288) void k_gru(
        const __hip_bfloat16* __restrict__ gi,
        const float* __restrict__ whh,
        const float* __restrict__ bhh,
        __hip_bfloat16* __restrict__ hout,
        int t0, int TC, int u)
{
    const int nl = blockIdx.x;
    const int j = threadIdx.x;           // 0..287
    __shared__ __align__(16) float h_l[96];
    __shared__ float bufz[96], bufni[96], bufnh[96];
    float w[96];
    {
        const float* wr = whh + (size_t)j * 96;
#pragma unroll
        for (int k = 0; k < 96; ++k) w[k] = wr[k];
    }
    const float bj = bhh[j];
    if (j < 96) h_l[j] = 0.f;
    __syncthreads();
    for (int s = 0; s < 128; ++s) {
        const int i = u ? (127 - s) : s;
        const float gv = (float)gi[((size_t)i * TC + nl) * 288 + j];
        float gh = bj;
        const float4* h4 = (const float4*)(&h_l[0]);
#pragma unroll
        for (int q = 0; q < 24; ++q) {
            float4 hv = h4[q];
            gh += hv.x * w[4 * q] + hv.y * w[4 * q + 1] + hv.z * w[4 * q + 2] + hv.w * w[4 * q + 3];
        }
        if (j >= 192)      { bufni[j - 192] = gv; bufnh[j - 192] = gh; }
        else if (j >= 96)  { bufz[j - 96] = gv + gh; }
        __syncthreads();
        if (j < 96) {
            float rg = 1.f / (1.f + __expf(-(gv + gh)));
            float zg = 1.f / (1.f + __expf(-bufz[j]));
            float ng = tanhf(bufni[j] + rg * bufnh[j]);
            float hn = (1.f - zg) * ng + zg * h_l[j];
            h_l[j] = hn;
            hout[((size_t)i * T_ + (t0 + nl)) * HC + u * 96 + j] = __float2bfloat16(hn);
        }
        __syncthreads();
    }
}

// ---------------------------------------------------------------------------
// Kernel C1: tt = tanh(h @ A1 + b1)    M=102400, K=192, N=50 (pad 64), MFMA
// ---------------------------------------------------------------------------
__global__ __launch_bounds__(256) void k_att1(
        const __hip_bfloat16* __restrict__ h,
        const float* __restrict__ A1,
        const float* __restrict__ b1,
        __hip_bfloat16* __restrict__ tt)
{
    const int m0 = blockIdx.x * 64;      // 1600 blocks
    const int tid = threadIdx.x;
    __shared__ __align__(16) unsigned short At[64 * 200];
    __shared__ __align__(16) unsigned short Bhi[64 * 200];
    __shared__ __align__(16) unsigned short Blo[64 * 200];
    for (int idx = tid; idx < 64 * 96; idx += 256) {
        int r = idx / 96, p = idx - r * 96;
        unsigned int v = *(const unsigned int*)((const unsigned short*)h + ((size_t)(m0 + r) * HC + 2 * p));
        *(unsigned int*)(&At[r * 200 + 2 * p]) = v;
    }
    for (int idx = tid; idx < 64 * 192; idx += 256) {
        int nn = idx / 192, k = idx - nn * 192;
        unsigned short vh = 0, vl = 0;
        if (nn < 50) split_hilo(A1[k * 50 + nn], vh, vl);   // transpose A1 -> B[n][k]
        Bhi[nn * 200 + k] = vh;
        Blo[nn * 200 + k] = vl;
    }
    __syncthreads();
    const int w = tid >> 6, l = tid & 63;
    const int lr = l & 15, quad = l >> 4;
    f32x4 z4 = {0.f, 0.f, 0.f, 0.f};
    f32x4 acc[4];
#pragma unroll
    for (int i = 0; i < 4; ++i) acc[i] = z4;
#pragma unroll
    for (int kk = 0; kk < 6; ++kk) {
        bf16x8 af = *(const bf16x8*)(&At[(w * 16 + lr) * 200 + kk * 32 + quad * 8]);
#pragma unroll
        for (int ns = 0; ns < 4; ++ns) {
            bf16x8 bh = *(const bf16x8*)(&Bhi[(ns * 16 + lr) * 200 + kk * 32 + quad * 8]);
            bf16x8 bl = *(const bf16x8*)(&Blo[(ns * 16 + lr) * 200 + kk * 32 + quad * 8]);
            acc[ns] = __builtin_amdgcn_mfma_f32_16x16x32_bf16(af, bh, acc[ns], 0, 0, 0);
            acc[ns] = __builtin_amdgcn_mfma_f32_16x16x32_bf16(af, bl, acc[ns], 0, 0, 0);
        }
    }
#pragma unroll
    for (int ns = 0; ns < 4; ++ns) {
        int col = ns * 16 + lr;
        if (col < 50) {
            float bias = b1[col];
#pragma unroll
            for (int r2 = 0; r2 < 4; ++r2) {
                int grow = m0 + w * 16 + quad * 4 + r2;
                tt[(size_t)grow * 50 + col] = __float2bfloat16(tanhf(acc[ns][r2] + bias));
            }
        }
    }
}

// ---------------------------------------------------------------------------
// Kernel C2: att = softmax(tt @ A2 + b2, axis=-1)   one row per lane
// ---------------------------------------------------------------------------
__global__ __launch_bounds__(256) void k_att2(
        const __hip_bfloat16* __restrict__ tt,
        const float* __restrict__ A2,
        const float* __restrict__ b2,
        float* __restrict__ att)
{
    __shared__ float A2l[600];
    __shared__ float b2l[12];
    const int tid = threadIdx.x;
    for (int idx = tid; idx < 600; idx += 256) A2l[idx] = A2[idx];
    if (tid < 12) b2l[tid] = b2[tid];
    __syncthreads();
    const int row = blockIdx.x * 256 + tid;    // 400*256 == 102400 exact
    float acc[12];
#pragma unroll
    for (int r = 0; r < 12; ++r) acc[r] = b2l[r];
    const __hip_bfloat16* trow = tt + (size_t)row * 50;
    for (int jj = 0; jj < 50; ++jj) {
        float tv = (float)trow[jj];
#pragma unroll
        for (int r = 0; r < 12; ++r) acc[r] += tv * A2l[jj * 12 + r];
    }
    float mx = acc[0];
#pragma unroll
    for (int r = 1; r < 12; ++r) mx = fmaxf(mx, acc[r]);
    float sm = 0.f;
#pragma unroll
    for (int r = 0; r < 12; ++r) { acc[r] = __expf(acc[r] - mx); sm += acc[r]; }
    float inv = 1.f / sm;
#pragma unroll
    for (int r = 0; r < 12; ++r) att[(size_t)row * 12 + r] = acc[r] * inv;
}

// ---------------------------------------------------------------------------
// Kernel D: per-batch caps (Wcaps fp32, out fp32).
// T=800 handled as 13 tiles of 64 with ZERO-PADDED tail (t0=768 -> 32 valid).
// ---------------------------------------------------------------------------
__global__ __launch_bounds__(256) void k_caps(
        const __hip_bfloat16* __restrict__ h,
        const float* __restrict__ att,
        const float* __restrict__ Wcaps,
        float* __restrict__ out,
        float* __restrict__ norms)
{
    const int b = blockIdx.x;
    const int tid = threadIdx.x;
    __shared__ __align__(16) unsigned short hT[64 * 192];
    __shared__ float attT[64 * 12];
    __shared__ float m_l[12 * 192];
    __shared__ float g_l[144];
    __shared__ float u_l[9600];
    __shared__ float blogl[600];
    __shared__ float c_l[600];
    __shared__ float s_l[800];
    __shared__ float v_l[800];
    __shared__ float scl[64];

    float macc[12];
#pragma unroll
    for (int r = 0; r < 12; ++r) macc[r] = 0.f;
    float gacc[3] = {0.f, 0.f, 0.f};

    for (int t0 = 0; t0 < T_; t0 += 64) {
        __syncthreads();
        for (int idx = tid; idx < 64 * 96; idx += 256) {
            int rr = idx / 96, p = idx - rr * 96;
            unsigned int v = 0;
            if (t0 + rr < T_)   // zero-pad tail tile (800 = 12*64 + 32)
                v = *(const unsigned int*)((const unsigned short*)h +
                                ((size_t)(b * T_ + t0 + rr) * HC + 2 * p));
            *(unsigned int*)(&hT[rr * 192 + 2 * p]) = v;
        }
        for (int idx = tid; idx < 64 * 12; idx += 256) {
            int rr = idx / 12;
            attT[idx] = (t0 + rr < T_) ? att[(size_t)(b * T_ + t0) * 12 + idx] : 0.f;
        }
        __syncthreads();
        if (tid < 192) {
            for (int t2 = 0; t2 < 64; ++t2) {
                float hv = (float)(*(const __hip_bfloat16*)(&hT[t2 * 192 + tid]));
#pragma unroll
                for (int r = 0; r < 12; ++r) macc[r] += hv * attT[t2 * 12 + r];
            }
        } else {
            int e = tid - 192;
#pragma unroll
            for (int q = 0; q < 3; ++q) {
                int idx = e + 64 * q;
                if (idx < 144) {
                    int rr = idx / 12, ss = idx - rr * 12;
                    float s2 = 0.f;
                    for (int t2 = 0; t2 < 64; ++t2) s2 += attT[t2 * 12 + rr] * attT[t2 * 12 + ss];
                    gacc[q] += s2;
                }
            }
        }
    }
    __syncthreads();
    if (tid < 192) { for (int r = 0; r < 12; ++r) m_l[r * 192 + tid] = macc[r]; }
    else {
        int e = tid - 192;
#pragma unroll
        for (int q = 0; q < 3; ++q) { int idx = e + 64 * q; if (idx < 144) g_l[idx] = gacc[q]; }
    }
    __syncthreads();
    if (tid == 0) {
        float s2 = 0.f;
        for (int idx = 0; idx < 144; ++idx) {
            float v = g_l[idx] - ((idx / 12 == idx % 12) ? 1.f : 0.f);
            s2 += v * v;
        }
        norms[b] = sqrtf(s2);
    }
    if (tid < 12) {
        float n2 = 0.f;
        for (int i = 0; i < 192; ++i) { float v = m_l[tid * 192 + i]; n2 += v * v; }
        scl[tid] = squash_scale(n2);
    }
    __syncthreads();
    if (tid < 192) { for (int r = 0; r < 12; ++r) m_l[r * 192 + tid] *= scl[r]; }
    __syncthreads();
    // u_hat[r][c][o] = sum_i v0[r][i] * Wcaps[r][i][c][o]   (Wcaps fp32)
    for (int e = tid; e < 9600; e += 256) {
        int r = e / 800;
        int rem = e - r * 800;           // c*16+o
        const float* wp = Wcaps + (size_t)r * 192 * 800 + rem;
        const float* v0p = &m_l[r * 192];
        float a = 0.f;
        for (int i = 0; i < 192; ++i) a += v0p[i] * wp[(size_t)i * 800];
        u_l[e] = a;
    }
    for (int e = tid; e < 600; e += 256) blogl[e] = 0.f;
    __syncthreads();
    for (int it = 0; it < 3; ++it) {
        if (tid < 12) {
            float mx = -1e30f;
            for (int cc = 0; cc < 50; ++cc) mx = fmaxf(mx, blogl[tid * 50 + cc]);
            float sm = 0.f;
            for (int cc = 0; cc < 50; ++cc) {
                float e2 = __expf(blogl[tid * 50 + cc] - mx);
                c_l[tid * 50 + cc] = e2; sm += e2;
            }
            float inv = 1.f / sm;
            for (int cc = 0; cc < 50; ++cc) c_l[tid * 50 + cc] *= inv;
        }
        __syncthreads();
        for (int e = tid; e < 800; e += 256) {
            int cc = e >> 4;
            float sv = 0.f;
#pragma unroll
            for (int r = 0; r < 12; ++r) sv += c_l[r * 50 + cc] * u_l[r * 800 + e];
            s_l[e] = sv;
        }
        __syncthreads();
        for (int cc = tid; cc < 50; cc += 256) {
            float n2 = 0.f;
#pragma unroll
            for (int o = 0; o < 16; ++o) { float v = s_l[cc * 16 + o]; n2 += v * v; }
            scl[cc] = squash_scale(n2);
        }
        __syncthreads();
        for (int e = tid; e < 800; e += 256) v_l[e] = s_l[e] * scl[e >> 4];
        __syncthreads();
        if (it < 2) {
            for (int e = tid; e < 600; e += 256) {
                int cc = e % 50;
                float dd = 0.f;
#pragma unroll
                for (int o = 0; o < 16; ++o) dd += u_l[e * 16 + o] * v_l[cc * 16 + o];
                blogl[e] += dd;
            }
            __syncthreads();
        }
    }
    for (int e = tid; e < 800; e += 256) out[(size_t)b * 800 + e] = v_l[e];
}

// ---------------------------------------------------------------------------
// Kernel E: att_reg = mean(norms)
// ---------------------------------------------------------------------------
__global__ void k_reg(const float* __restrict__ norms, float* __restrict__ out)
{
    const int l = threadIdx.x;           // 64
    float v = norms[l] + norms[l + 64];
#pragma unroll
    for (int off = 32; off; off >>= 1) v += __shfl_down(v, off);
    if (l == 0) out[OUTV] = v * (1.f / 128.f);
}

// ---------------------------------------------------------------------------
extern "C" void kernel_launch(void* const* d_in, const int* in_sizes, int n_in,
                              void* d_out, int out_size, void* d_ws, size_t ws_size,
                              hipStream_t stream) {
    const int*   tokens = (const int*)d_in[0];
    const float* emb    = (const float*)d_in[1];
    const float* wih_f  = (const float*)d_in[2];
    const float* whh_f  = (const float*)d_in[3];
    const float* bih_f  = (const float*)d_in[4];
    const float* bhh_f  = (const float*)d_in[5];
    const float* wih_b  = (const float*)d_in[6];
    const float* whh_b  = (const float*)d_in[7];
    const float* bih_b  = (const float*)d_in[8];
    const float* bhh_b  = (const float*)d_in[9];
    const float* A1     = (const float*)d_in[10];
    const float* b1     = (const float*)d_in[11];
    const float* A2     = (const float*)d_in[12];
    const float* b2     = (const float*)d_in[13];
    const float* Wc     = (const float*)d_in[14];

    // Adaptive workspace layout (depends only on ws_size -> identical every call).
    const size_t HB = 39321600;                  // hbuf: 102400*192*2 (bf16)
    char* ws = (char*)d_ws;
    __hip_bfloat16* hbuf = (__hip_bfloat16*)ws;
    char* region2 = ws + HB;
    int TC;
    if      (ws_size >= HB + (size_t)128 * 800 * 288 * 2) TC = 800;  // 98.3 MB total
    else if (ws_size >= HB + (size_t)128 * 400 * 288 * 2) TC = 400;  // 68.8 MB
    else                                                  TC = 200;  // 54.5 MB
    __hip_bfloat16* gi  = (__hip_bfloat16*)region2;
    __hip_bfloat16* tt  = (__hip_bfloat16*)region2;                  // reuses gi space
    float*          att = (float*)(region2 + 10240000);
    float*          nrm = (float*)(region2 + 15155200);
    float*          out = (float*)d_out;

    for (int u = 0; u < 2; ++u) {
        const float* wih = u ? wih_b : wih_f;
        const float* whh = u ? whh_b : whh_f;
        const float* bih = u ? bih_b : bih_f;
        const float* bhh = u ? bhh_b : bhh_f;
        for (int t0 = 0; t0 < T_; t0 += TC) {
            k_gi <<<dim3(128 * TC / 64, 5), 256, 0, stream>>>(tokens, emb, wih, bih, gi, t0, TC);
            k_gru<<<TC, 288, 0, stream>>>(gi, whh, bhh, hbuf, t0, TC, u);
        }
    }
    k_att1<<<1600, 256, 0, stream>>>(hbuf, A1, b1, tt);
    k_att2<<<400, 256, 0, stream>>>(tt, A2, b2, att);
    k_caps<<<128, 256, 0, stream>>>(hbuf, att, Wc, out, nrm);
    k_reg <<<1, 64, 0, stream>>>(nrm, out);
}

// Round 6
// 1224.515 us; speedup vs baseline: 1.1813x; 1.1813x over previous
//
#include <hip/hip_runtime.h>
#include <hip/hip_bf16.h>
#include <math.h>

typedef short bf16x8 __attribute__((ext_vector_type(8)));
typedef float f32x4 __attribute__((ext_vector_type(4)));

#define B_   128
#define T_   800
#define E_   100
#define HC   192       // 2H
#define OUTV 102400    // B*C*O

__device__ inline float squash_scale(float n2) {
    return (n2 / (n2 + 1.f)) * rsqrtf(fmaxf(n2, 1e-30f));
}

__device__ inline unsigned short bf16_bits(float x) {
    __hip_bfloat16 h = __float2bfloat16(x);
    return *(unsigned short*)&h;
}

__device__ inline unsigned int pack_bf16x2(float a, float b) {
    return (unsigned int)bf16_bits(a) | ((unsigned int)bf16_bits(b) << 16);
}

// split x into hi (bf16) + lo (bf16 of residual)
__device__ inline void split_hilo(float x, unsigned short& hi, unsigned short& lo) {
    __hip_bfloat16 h = __float2bfloat16(x);
    float hf = __bfloat162float(h);
    hi = *(unsigned short*)&h;
    __hip_bfloat16 l = __float2bfloat16(x - hf);
    lo = *(unsigned short*)&l;
}

// ---------------------------------------------------------------------------
// Kernel A: gi = gather(emb, tokens[chunk]) @ wih^T + bih  for ONE direction.
// ---------------------------------------------------------------------------
__global__ __launch_bounds__(256) void k_gi(const int* __restrict__ tokens,
        const float* __restrict__ emb,
        const float* __restrict__ wih,
        const float* __restrict__ bih,
        __hip_bfloat16* __restrict__ gi,
        int t0, int TC)
{
    const int m0 = blockIdx.x * 64;
    const int n0 = blockIdx.y * 64;      // 0,64,128,192,256
    const int tid = threadIdx.x;
    __shared__ __align__(16) unsigned short At[64 * 136];   // 64 x 128, stride 136
    __shared__ __align__(16) unsigned short Bhi[64 * 136];
    __shared__ __align__(16) unsigned short Blo[64 * 136];
    __shared__ int tok[64];
    if (tid < 64) {
        int cr = m0 + tid;
        tok[tid] = tokens[(cr / TC) * T_ + t0 + (cr % TC)];
    }
    __syncthreads();
    for (int idx = tid; idx < 64 * 64; idx += 256) {
        int r = idx >> 6, p = idx & 63;          // p = column pair
        unsigned int v = 0;
        if (p < 50) {
            float2 f = *(const float2*)(emb + (size_t)tok[r] * E_ + 2 * p);
            v = pack_bf16x2(f.x, f.y);
        }
        *(unsigned int*)(&At[r * 136 + 2 * p]) = v;
    }
    for (int idx = tid; idx < 64 * 64; idx += 256) {
        int nn = idx >> 6, p = idx & 63;
        int gc = n0 + nn;
        unsigned int vh = 0, vl = 0;
        if (p < 50 && gc < 288) {
            float2 f = *(const float2*)(wih + (size_t)gc * E_ + 2 * p);
            unsigned short h0, l0, h1, l1;
            split_hilo(f.x, h0, l0);
            split_hilo(f.y, h1, l1);
            vh = (unsigned int)h0 | ((unsigned int)h1 << 16);
            vl = (unsigned int)l0 | ((unsigned int)l1 << 16);
        }
        *(unsigned int*)(&Bhi[nn * 136 + 2 * p]) = vh;
        *(unsigned int*)(&Blo[nn * 136 + 2 * p]) = vl;
    }
    __syncthreads();
    const int w = tid >> 6, l = tid & 63;
    const int lr = l & 15, quad = l >> 4;
    f32x4 z4 = {0.f, 0.f, 0.f, 0.f};
    f32x4 acc[4];
#pragma unroll
    for (int i = 0; i < 4; ++i) acc[i] = z4;
#pragma unroll
    for (int kk = 0; kk < 4; ++kk) {
        bf16x8 af = *(const bf16x8*)(&At[(w * 16 + lr) * 136 + kk * 32 + quad * 8]);
#pragma unroll
        for (int ns = 0; ns < 4; ++ns) {
            bf16x8 bh = *(const bf16x8*)(&Bhi[(ns * 16 + lr) * 136 + kk * 32 + quad * 8]);
            bf16x8 bl = *(const bf16x8*)(&Blo[(ns * 16 + lr) * 136 + kk * 32 + quad * 8]);
            acc[ns] = __builtin_amdgcn_mfma_f32_16x16x32_bf16(af, bh, acc[ns], 0, 0, 0);
            acc[ns] = __builtin_amdgcn_mfma_f32_16x16x32_bf16(af, bl, acc[ns], 0, 0, 0);
        }
    }
#pragma unroll
    for (int ns = 0; ns < 4; ++ns) {
        int gcol = n0 + ns * 16 + lr;
        if (gcol < 288) {
            float bias = bih[gcol];
#pragma unroll
            for (int r2 = 0; r2 < 4; ++r2) {
                int grow = m0 + w * 16 + quad * 4 + r2;
                gi[(size_t)grow * 288 + gcol] = __float2bfloat16(acc[ns][r2] + bias);
            }
        }
    }
}

// ---------------------------------------------------------------------------
// Kernel B: GRU recurrence for ONE direction, chains t0..t0+TC-1.
// ---------------------------------------------------------------------------
__global__ __launch_bounds__(288) void k_gru(
        const __hip_bfloat16* __restrict__ gi,
        const float* __restrict__ whh,
        const float* __restrict__ bhh,
        __hip_bfloat16* __restrict__ hout,
        int t0, int TC, int u)
{
    const int nl = blockIdx.x;
    const int j = threadIdx.x;           // 0..287
    __shared__ __align__(16) float h_l[96];
    __shared__ float bufz[96], bufni[96], bufnh[96];
    float w[96];
    {
        const float* wr = whh + (size_t)j * 96;
#pragma unroll
        for (int k = 0; k < 96; ++k) w[k] = wr[k];
    }
    const float bj = bhh[j];
    if (j < 96) h_l[j] = 0.f;
    __syncthreads();
    for (int s = 0; s < 128; ++s) {
        const int i = u ? (127 - s) : s;
        const float gv = (float)gi[((size_t)i * TC + nl) * 288 + j];
        float gh = bj;
        const float4* h4 = (const float4*)(&h_l[0]);
#pragma unroll
        for (int q = 0; q < 24; ++q) {
            float4 hv = h4[q];
            gh += hv.x * w[4 * q] + hv.y * w[4 * q + 1] + hv.z * w[4 * q + 2] + hv.w * w[4 * q + 3];
        }
        if (j >= 192)      { bufni[j - 192] = gv; bufnh[j - 192] = gh; }
        else if (j >= 96)  { bufz[j - 96] = gv + gh; }
        __syncthreads();
        if (j < 96) {
            float rg = 1.f / (1.f + __expf(-(gv + gh)));
            float zg = 1.f / (1.f + __expf(-bufz[j]));
            float ng = tanhf(bufni[j] + rg * bufnh[j]);
            float hn = (1.f - zg) * ng + zg * h_l[j];
            h_l[j] = hn;
            hout[((size_t)i * T_ + (t0 + nl)) * HC + u * 96 + j] = __float2bfloat16(hn);
        }
        __syncthreads();
    }
}

// ---------------------------------------------------------------------------
// Kernel C1: tt = tanh(h @ A1 + b1)    M=102400, K=192, N=50 (pad 64), MFMA
// ---------------------------------------------------------------------------
__global__ __launch_bounds__(256) void k_att1(
        const __hip_bfloat16* __restrict__ h,
        const float* __restrict__ A1,
        const float* __restrict__ b1,
        __hip_bfloat16* __restrict__ tt)
{
    const int m0 = blockIdx.x * 64;      // 1600 blocks
    const int tid = threadIdx.x;
    __shared__ __align__(16) unsigned short At[64 * 200];
    __shared__ __align__(16) unsigned short Bhi[64 * 200];
    __shared__ __align__(16) unsigned short Blo[64 * 200];
    for (int idx = tid; idx < 64 * 96; idx += 256) {
        int r = idx / 96, p = idx - r * 96;
        unsigned int v = *(const unsigned int*)((const unsigned short*)h + ((size_t)(m0 + r) * HC + 2 * p));
        *(unsigned int*)(&At[r * 200 + 2 * p]) = v;
    }
    for (int idx = tid; idx < 64 * 192; idx += 256) {
        int nn = idx / 192, k = idx - nn * 192;
        unsigned short vh = 0, vl = 0;
        if (nn < 50) split_hilo(A1[k * 50 + nn], vh, vl);   // transpose A1 -> B[n][k]
        Bhi[nn * 200 + k] = vh;
        Blo[nn * 200 + k] = vl;
    }
    __syncthreads();
    const int w = tid >> 6, l = tid & 63;
    const int lr = l & 15, quad = l >> 4;
    f32x4 z4 = {0.f, 0.f, 0.f, 0.f};
    f32x4 acc[4];
#pragma unroll
    for (int i = 0; i < 4; ++i) acc[i] = z4;
#pragma unroll
    for (int kk = 0; kk < 6; ++kk) {
        bf16x8 af = *(const bf16x8*)(&At[(w * 16 + lr) * 200 + kk * 32 + quad * 8]);
#pragma unroll
        for (int ns = 0; ns < 4; ++ns) {
            bf16x8 bh = *(const bf16x8*)(&Bhi[(ns * 16 + lr) * 200 + kk * 32 + quad * 8]);
            bf16x8 bl = *(const bf16x8*)(&Blo[(ns * 16 + lr) * 200 + kk * 32 + quad * 8]);
            acc[ns] = __builtin_amdgcn_mfma_f32_16x16x32_bf16(af, bh, acc[ns], 0, 0, 0);
            acc[ns] = __builtin_amdgcn_mfma_f32_16x16x32_bf16(af, bl, acc[ns], 0, 0, 0);
        }
    }
#pragma unroll
    for (int ns = 0; ns < 4; ++ns) {
        int col = ns * 16 + lr;
        if (col < 50) {
            float bias = b1[col];
#pragma unroll
            for (int r2 = 0; r2 < 4; ++r2) {
                int grow = m0 + w * 16 + quad * 4 + r2;
                tt[(size_t)grow * 50 + col] = __float2bfloat16(tanhf(acc[ns][r2] + bias));
            }
        }
    }
}

// ---------------------------------------------------------------------------
// Kernel C2: att = softmax(tt @ A2 + b2, axis=-1)   one row per lane
// ---------------------------------------------------------------------------
__global__ __launch_bounds__(256) void k_att2(
        const __hip_bfloat16* __restrict__ tt,
        const float* __restrict__ A2,
        const float* __restrict__ b2,
        float* __restrict__ att)
{
    __shared__ float A2l[600];
    __shared__ float b2l[12];
    const int tid = threadIdx.x;
    for (int idx = tid; idx < 600; idx += 256) A2l[idx] = A2[idx];
    if (tid < 12) b2l[tid] = b2[tid];
    __syncthreads();
    const int row = blockIdx.x * 256 + tid;    // 400*256 == 102400 exact
    float acc[12];
#pragma unroll
    for (int r = 0; r < 12; ++r) acc[r] = b2l[r];
    const __hip_bfloat16* trow = tt + (size_t)row * 50;
    for (int jj = 0; jj < 50; ++jj) {
        float tv = (float)trow[jj];
#pragma unroll
        for (int r = 0; r < 12; ++r) acc[r] += tv * A2l[jj * 12 + r];
    }
    float mx = acc[0];
#pragma unroll
    for (int r = 1; r < 12; ++r) mx = fmaxf(mx, acc[r]);
    float sm = 0.f;
#pragma unroll
    for (int r = 0; r < 12; ++r) { acc[r] = __expf(acc[r] - mx); sm += acc[r]; }
    float inv = 1.f / sm;
#pragma unroll
    for (int r = 0; r < 12; ++r) att[(size_t)row * 12 + r] = acc[r] * inv;
}

// ---------------------------------------------------------------------------
// Kernel D1: per-batch pooling: m = att^T h, g = att^T att, squash -> v0, nrm
// (pooling/g logic identical to the round-5 verified k_caps)
// ---------------------------------------------------------------------------
__global__ __launch_bounds__(256) void k_pool(
        const __hip_bfloat16* __restrict__ h,
        const float* __restrict__ att,
        float* __restrict__ v0g,      // [128][12][192] fp32
        float* __restrict__ norms)
{
    const int b = blockIdx.x;
    const int tid = threadIdx.x;
    __shared__ __align__(16) unsigned short hT[64 * 192];
    __shared__ float attT[64 * 12];
    __shared__ float m_l[12 * 192];
    __shared__ float g_l[144];
    __shared__ float scl[12];

    float macc[12];
#pragma unroll
    for (int r = 0; r < 12; ++r) macc[r] = 0.f;
    float gacc[3] = {0.f, 0.f, 0.f};

    for (int t0 = 0; t0 < T_; t0 += 64) {
        __syncthreads();
        for (int idx = tid; idx < 64 * 96; idx += 256) {
            int rr = idx / 96, p = idx - rr * 96;
            unsigned int v = 0;
            if (t0 + rr < T_)   // zero-pad tail tile (800 = 12*64 + 32)
                v = *(const unsigned int*)((const unsigned short*)h +
                                ((size_t)(b * T_ + t0 + rr) * HC + 2 * p));
            *(unsigned int*)(&hT[rr * 192 + 2 * p]) = v;
        }
        for (int idx = tid; idx < 64 * 12; idx += 256) {
            int rr = idx / 12;
            attT[idx] = (t0 + rr < T_) ? att[(size_t)(b * T_ + t0) * 12 + idx] : 0.f;
        }
        __syncthreads();
        if (tid < 192) {
            for (int t2 = 0; t2 < 64; ++t2) {
                float hv = (float)(*(const __hip_bfloat16*)(&hT[t2 * 192 + tid]));
#pragma unroll
                for (int r = 0; r < 12; ++r) macc[r] += hv * attT[t2 * 12 + r];
            }
        } else {
            int e = tid - 192;
#pragma unroll
            for (int q = 0; q < 3; ++q) {
                int idx = e + 64 * q;
                if (idx < 144) {
                    int rr = idx / 12, ss = idx - rr * 12;
                    float s2 = 0.f;
                    for (int t2 = 0; t2 < 64; ++t2) s2 += attT[t2 * 12 + rr] * attT[t2 * 12 + ss];
                    gacc[q] += s2;
                }
            }
        }
    }
    __syncthreads();
    if (tid < 192) { for (int r = 0; r < 12; ++r) m_l[r * 192 + tid] = macc[r]; }
    else {
        int e = tid - 192;
#pragma unroll
        for (int q = 0; q < 3; ++q) { int idx = e + 64 * q; if (idx < 144) g_l[idx] = gacc[q]; }
    }
    __syncthreads();
    if (tid == 0) {
        float s2 = 0.f;
        for (int idx = 0; idx < 144; ++idx) {
            float v = g_l[idx] - ((idx / 12 == idx % 12) ? 1.f : 0.f);
            s2 += v * v;
        }
        norms[b] = sqrtf(s2);
    }
    if (tid < 12) {
        float n2 = 0.f;
        for (int i = 0; i < 192; ++i) { float v = m_l[tid * 192 + i]; n2 += v * v; }
        scl[tid] = squash_scale(n2);
    }
    __syncthreads();
    if (tid < 192) {
#pragma unroll
        for (int r = 0; r < 12; ++r)
            v0g[((size_t)b * 12 + r) * 192 + tid] = m_l[r * 192 + tid] * scl[r];
    }
}

// ---------------------------------------------------------------------------
// Kernel D2: u_hat[b][r][cco] = sum_i v0[b][r][i] * Wcaps[r][i][cco]
// MFMA GEMM per r: [128 x 192] @ [192 x 800]. Grid (12, 2, 13), 64x64 tiles.
// Wcaps read ONCE total (vs 128x in the fused version).
// ---------------------------------------------------------------------------
__global__ __launch_bounds__(256) void k_uhat(
        const float* __restrict__ v0g,
        const float* __restrict__ Wc,
        float* __restrict__ u_hat)    // [128][12][800] fp32
{
    const int r  = blockIdx.x;           // 0..11
    const int m0 = blockIdx.y * 64;      // 0,64
    const int n0 = blockIdx.z * 64;      // 0..768 (tail tile 32 valid)
    const int tid = threadIdx.x;
    __shared__ __align__(16) unsigned short At[64 * 200];
    __shared__ __align__(16) unsigned short Bt[64 * 200];
    for (int idx = tid; idx < 64 * 96; idx += 256) {
        int row = idx / 96, p = idx - row * 96;
        float2 f = *(const float2*)(v0g + ((size_t)(m0 + row) * 12 + r) * 192 + 2 * p);
        *(unsigned int*)(&At[row * 200 + 2 * p]) = pack_bf16x2(f.x, f.y);
    }
    for (int idx = tid; idx < 192 * 64; idx += 256) {
        int k = idx >> 6, nn = idx & 63;      // consecutive tid -> consecutive nn (coalesced)
        unsigned short v = 0;
        if (n0 + nn < 800) v = bf16_bits(Wc[((size_t)r * 192 + k) * 800 + n0 + nn]);
        Bt[nn * 200 + k] = v;
    }
    __syncthreads();
    const int w = tid >> 6, l = tid & 63;
    const int lr = l & 15, quad = l >> 4;
    f32x4 z4 = {0.f, 0.f, 0.f, 0.f};
    f32x4 acc[4];
#pragma unroll
    for (int i = 0; i < 4; ++i) acc[i] = z4;
#pragma unroll
    for (int kk = 0; kk < 6; ++kk) {
        bf16x8 af = *(const bf16x8*)(&At[(w * 16 + lr) * 200 + kk * 32 + quad * 8]);
#pragma unroll
        for (int ns = 0; ns < 4; ++ns) {
            bf16x8 bv = *(const bf16x8*)(&Bt[(ns * 16 + lr) * 200 + kk * 32 + quad * 8]);
            acc[ns] = __builtin_amdgcn_mfma_f32_16x16x32_bf16(af, bv, acc[ns], 0, 0, 0);
        }
    }
#pragma unroll
    for (int ns = 0; ns < 4; ++ns) {
        int cco = n0 + ns * 16 + lr;
        if (cco < 800) {
#pragma unroll
            for (int r2 = 0; r2 < 4; ++r2) {
                int brow = m0 + w * 16 + quad * 4 + r2;
                u_hat[((size_t)brow * 12 + r) * 800 + cco] = acc[ns][r2];
            }
        }
    }
}

// ---------------------------------------------------------------------------
// Kernel D3: dynamic routing per batch (u_hat in LDS), 3 iterations, write v.
// ---------------------------------------------------------------------------
__global__ __launch_bounds__(256) void k_route(
        const float* __restrict__ u_hat,
        float* __restrict__ out)
{
    const int b = blockIdx.x;
    const int tid = threadIdx.x;
    __shared__ __align__(16) float u_l[9600];
    __shared__ float blogl[600];
    __shared__ float c_l[600];
    __shared__ float s_l[800];
    __shared__ float v_l[800];
    __shared__ float scl[64];
    {
        const float4* src = (const float4*)(u_hat + (size_t)b * 9600);
        float4* dst = (float4*)u_l;
        for (int e = tid; e < 2400; e += 256) dst[e] = src[e];
    }
    for (int e = tid; e < 600; e += 256) blogl[e] = 0.f;
    __syncthreads();
    for (int it = 0; it < 3; ++it) {
        if (tid < 12) {
            float mx = -1e30f;
            for (int cc = 0; cc < 50; ++cc) mx = fmaxf(mx, blogl[tid * 50 + cc]);
            float sm = 0.f;
            for (int cc = 0; cc < 50; ++cc) {
                float e2 = __expf(blogl[tid * 50 + cc] - mx);
                c_l[tid * 50 + cc] = e2; sm += e2;
            }
            float inv = 1.f / sm;
            for (int cc = 0; cc < 50; ++cc) c_l[tid * 50 + cc] *= inv;
        }
        __syncthreads();
        for (int e = tid; e < 800; e += 256) {
            int cc = e >> 4;
            float sv = 0.f;
#pragma unroll
            for (int r = 0; r < 12; ++r) sv += c_l[r * 50 + cc] * u_l[r * 800 + e];
            s_l[e] = sv;
        }
        __syncthreads();
        for (int cc = tid; cc < 50; cc += 256) {
            float n2 = 0.f;
#pragma unroll
            for (int o = 0; o < 16; ++o) { float v = s_l[cc * 16 + o]; n2 += v * v; }
            scl[cc] = squash_scale(n2);
        }
        __syncthreads();
        for (int e = tid; e < 800; e += 256) v_l[e] = s_l[e] * scl[e >> 4];
        __syncthreads();
        if (it < 2) {
            for (int e = tid; e < 600; e += 256) {
                int cc = e % 50;
                float dd = 0.f;
#pragma unroll
                for (int o = 0; o < 16; ++o) dd += u_l[e * 16 + o] * v_l[cc * 16 + o];
                blogl[e] += dd;
            }
            __syncthreads();
        }
    }
    for (int e = tid; e < 800; e += 256) out[(size_t)b * 800 + e] = v_l[e];
}

// ---------------------------------------------------------------------------
// Kernel E: att_reg = mean(norms)
// ---------------------------------------------------------------------------
__global__ void k_reg(const float* __restrict__ norms, float* __restrict__ out)
{
    const int l = threadIdx.x;           // 64
    float v = norms[l] + norms[l + 64];
#pragma unroll
    for (int off = 32; off; off >>= 1) v += __shfl_down(v, off);
    if (l == 0) out[OUTV] = v * (1.f / 128.f);
}

// ---------------------------------------------------------------------------
extern "C" void kernel_launch(void* const* d_in, const int* in_sizes, int n_in,
                              void* d_out, int out_size, void* d_ws, size_t ws_size,
                              hipStream_t stream) {
    const int*   tokens = (const int*)d_in[0];
    const float* emb    = (const float*)d_in[1];
    const float* wih_f  = (const float*)d_in[2];
    const float* whh_f  = (const float*)d_in[3];
    const float* bih_f  = (const float*)d_in[4];
    const float* bhh_f  = (const float*)d_in[5];
    const float* wih_b  = (const float*)d_in[6];
    const float* whh_b  = (const float*)d_in[7];
    const float* bih_b  = (const float*)d_in[8];
    const float* bhh_b  = (const float*)d_in[9];
    const float* A1     = (const float*)d_in[10];
    const float* b1     = (const float*)d_in[11];
    const float* A2     = (const float*)d_in[12];
    const float* b2     = (const float*)d_in[13];
    const float* Wc     = (const float*)d_in[14];

    // Adaptive workspace layout (depends only on ws_size -> identical every call).
    const size_t HB = 39321600;                  // hbuf: 102400*192*2 (bf16)
    char* ws = (char*)d_ws;
    __hip_bfloat16* hbuf = (__hip_bfloat16*)ws;
    char* region2 = ws + HB;
    int TC;
    if      (ws_size >= HB + (size_t)128 * 800 * 288 * 2) TC = 800;
    else if (ws_size >= HB + (size_t)128 * 400 * 288 * 2) TC = 400;
    else                                                  TC = 200;
    // region2 tail (all dead while gi is live; gi dead before tt written):
    // [tt 10,240,000][att 4,915,200][nrm 512][v0 1,179,648][u_hat 4,915,200]
    __hip_bfloat16* gi   = (__hip_bfloat16*)region2;
    __hip_bfloat16* tt   = (__hip_bfloat16*)region2;
    float*          att  = (float*)(region2 + 10240000);
    float*          nrm  = (float*)(region2 + 15155200);
    float*          v0g  = (float*)(region2 + 15155712);
    float*          uhat = (float*)(region2 + 16335360);
    float*          out  = (float*)d_out;

    for (int u = 0; u < 2; ++u) {
        const float* wih = u ? wih_b : wih_f;
        const float* whh = u ? whh_b : whh_f;
        const float* bih = u ? bih_b : bih_f;
        const float* bhh = u ? bhh_b : bhh_f;
        for (int t0 = 0; t0 < T_; t0 += TC) {
            k_gi <<<dim3(128 * TC / 64, 5), 256, 0, stream>>>(tokens, emb, wih, bih, gi, t0, TC);
            k_gru<<<TC, 288, 0, stream>>>(gi, whh, bhh, hbuf, t0, TC, u);
        }
    }
    k_att1 <<<1600, 256, 0, stream>>>(hbuf, A1, b1, tt);
    k_att2 <<<400, 256, 0, stream>>>(tt, A2, b2, att);
    k_pool <<<128, 256, 0, stream>>>(hbuf, att, v0g, nrm);
    k_uhat <<<dim3(12, 2, 13), 256, 0, stream>>>(v0g, Wc, uhat);
    k_route<<<128, 256, 0, stream>>>(uhat, out);
    k_reg  <<<1, 64, 0, stream>>>(nrm, out);
}